// Round 6
// baseline (189.661 us; speedup 1.0000x reference)
//
#include <hip/hip_runtime.h>
#include <math.h>

// Problem constants
#define KP   10      // prototypes per side
#define CC   768     // channels
#define NB   8       // batch
#define HW   4096    // 64*64
#define STOT 32768   // NB*HW
#define NS   12      // N_SAMPLES

// Workspace layout (float offsets)
#define WS_SCORE_FG 0
#define WS_SCORE_BG 32768
#define WS_SEL      65536   // 24 ints
#define WS_FEATS    65600   // 24*768 floats (pos 12 rows, then neg 12 rows)
#define WS_PFG      84032   // 10*768
#define WS_PBG      91712   // 10*768
// top-k candidates (2 sides x 384 u64) overlap WS_PFG: written by k_topk1,
// read by k_topk2, and only later clobbered by k_refine's pfg output. Safe.
#define WS_CAND     84032

typedef unsigned long long ull;

// ---------------- K1: per-pixel norm + max-sim scores ----------------
// 8 waves x 64 pixels; wave w covers channels [96w,96w+96).
// F is streamed with NON-TEMPORAL loads (protects the proto lines in L1)
// and software-pipelined one 8-channel round ahead. Protos read as
// uniform-address float4 vector loads (L1-broadcast hits once F is nt).
__global__ __launch_bounds__(512, 4) void k_scores(const float* __restrict__ fg,
                                                   const float* __restrict__ bg,
                                                   const float* __restrict__ F,
                                                   const float* __restrict__ M,
                                                   float* __restrict__ sfg,
                                                   float* __restrict__ sbg) {
    __shared__ float part[8][64][23];
    __shared__ float comb[64][23];

    const int tid  = threadIdx.x;
    const int w    = __builtin_amdgcn_readfirstlane(tid >> 6);  // wave id -> SGPR
    const int lane = tid & 63;
    const int s    = blockIdx.x * 64 + lane;
    const int n    = s >> 12, hw = s & 4095;
    const float* fp = F + ((size_t)n * CC) * HW + hw;
    const int cbase = w * 96;

    int z;  // opaque zero in a VGPR: keeps proto addresses on the vector path
    asm volatile("v_mov_b32 %0, 0" : "=v"(z));
    const float* fgz = fg + z;
    const float* bgz = bg + z;

    float afg[KP], abg[KP], norm2 = 0.f;
#pragma unroll
    for (int k = 0; k < KP; ++k) { afg[k] = 0.f; abg[k] = 0.f; }

    float fn[8];
#pragma unroll
    for (int j = 0; j < 8; ++j) fn[j] = __builtin_nontemporal_load(fp + (size_t)(cbase + j) * HW);

    for (int c0 = 0; c0 < 96; c0 += 8) {
        float f[8];
#pragma unroll
        for (int j = 0; j < 8; ++j) f[j] = fn[j];
        if (c0 + 8 < 96) {
#pragma unroll
            for (int j = 0; j < 8; ++j)
                fn[j] = __builtin_nontemporal_load(fp + (size_t)(cbase + c0 + 8 + j) * HW);
        }

#pragma unroll
        for (int k = 0; k < KP; ++k) {
            const float4* pq = (const float4*)(fgz + k * CC + cbase + c0);
            float4 a = pq[0], b = pq[1];
            float acc = afg[k];
            acc = fmaf(f[0], a.x, acc); acc = fmaf(f[1], a.y, acc);
            acc = fmaf(f[2], a.z, acc); acc = fmaf(f[3], a.w, acc);
            acc = fmaf(f[4], b.x, acc); acc = fmaf(f[5], b.y, acc);
            acc = fmaf(f[6], b.z, acc); acc = fmaf(f[7], b.w, acc);
            afg[k] = acc;
        }
#pragma unroll
        for (int k = 0; k < KP; ++k) {
            const float4* pq = (const float4*)(bgz + k * CC + cbase + c0);
            float4 a = pq[0], b = pq[1];
            float acc = abg[k];
            acc = fmaf(f[0], a.x, acc); acc = fmaf(f[1], a.y, acc);
            acc = fmaf(f[2], a.z, acc); acc = fmaf(f[3], a.w, acc);
            acc = fmaf(f[4], b.x, acc); acc = fmaf(f[5], b.y, acc);
            acc = fmaf(f[6], b.z, acc); acc = fmaf(f[7], b.w, acc);
            abg[k] = acc;
        }
#pragma unroll
        for (int j = 0; j < 8; ++j) norm2 = fmaf(f[j], f[j], norm2);
    }

#pragma unroll
    for (int k = 0; k < KP; ++k) { part[w][lane][k] = afg[k]; part[w][lane][10 + k] = abg[k]; }
    part[w][lane][20] = norm2;
    __syncthreads();

    // reduce 8 waves -> comb[pix][j], 64*21 = 1344 items over 512 threads
    for (int item = tid; item < 64 * 21; item += 512) {
        int pix = item / 21, j = item - pix * 21;
        float acc = 0.f;
#pragma unroll
        for (int ww = 0; ww < 8; ++ww) acc += part[ww][pix][j];
        comb[pix][j] = acc;
    }
    __syncthreads();

    if (tid < 64) {
        float mfg = comb[tid][0], mbg = comb[tid][10];
#pragma unroll
        for (int k = 1; k < KP; ++k) { mfg = fmaxf(mfg, comb[tid][k]); mbg = fmaxf(mbg, comb[tid][10 + k]); }
        float nc = fmaxf(sqrtf(comb[tid][20]), 1e-8f);
        int sp = blockIdx.x * 64 + tid;
        float m = fminf(fmaxf(M[sp], 0.f), 1.f);
        sfg[sp] = (1.f - mfg / nc) * m;
        sbg[sp] = (1.f - mbg / nc) * (1.f - m);
    }
}

// Order-preserving float->uint map, packed with ~index for exact
// (value desc, index asc) ordering under unsigned max.
__device__ __forceinline__ ull pack_key(float v, int idx) {
    unsigned u = __float_as_uint(v);
    u ^= (unsigned)((int)u >> 31) | 0x80000000u;
    return ((ull)u << 32) | (ull)(0xFFFFFFFFu - (unsigned)idx);
}

// ---------------- K2a: top-12 stage 1 (64 blocks: 32 per side) ----------------
__global__ __launch_bounds__(256) void k_topk1(const float* __restrict__ ws,
                                               ull* __restrict__ cand) {
    const int side = blockIdx.x >> 5, blk = blockIdx.x & 31;
    const float4* sc4 = (const float4*)(ws + (side == 0 ? WS_SCORE_FG : WS_SCORE_BG));
    const int tid = threadIdx.x;
    const int wave = tid >> 6, lane = tid & 63;

    const int i4 = blk * 256 + tid;
    float4 v4 = sc4[i4];
    ull kk[4];
    kk[0] = pack_key(v4.x, 4 * i4 + 0);
    kk[1] = pack_key(v4.y, 4 * i4 + 1);
    kk[2] = pack_key(v4.z, 4 * i4 + 2);
    kk[3] = pack_key(v4.w, 4 * i4 + 3);

    __shared__ ull wbest[4];
    __shared__ ull win_sh;

    for (int r = 0; r < NS; ++r) {
        ull b = kk[0];
#pragma unroll
        for (int q = 1; q < 4; ++q) b = (kk[q] > b) ? kk[q] : b;
#pragma unroll
        for (int m2 = 1; m2 < 64; m2 <<= 1) {
            ull o = __shfl_xor(b, m2, 64);
            b = (o > b) ? o : b;
        }
        if (lane == 0) wbest[wave] = b;
        __syncthreads();
        if (tid == 0) {
            ull m = wbest[0];
#pragma unroll
            for (int ww = 1; ww < 4; ++ww) m = (wbest[ww] > m) ? wbest[ww] : m;
            win_sh = m;
            cand[side * 384 + blk * NS + r] = m;
        }
        __syncthreads();
        ull win = win_sh;
#pragma unroll
        for (int q = 0; q < 4; ++q) { if (kk[q] == win) kk[q] = 0ull; }
    }
}

// ---------------- K2b: top-12 stage 2 (merge 384 candidates per side) ----------------
__global__ __launch_bounds__(384) void k_topk2(const ull* __restrict__ cand,
                                               int* __restrict__ sel) {
    const int side = blockIdx.x;
    const int tid = threadIdx.x;
    const int wave = tid >> 6, lane = tid & 63;

    ull key = cand[side * 384 + tid];

    __shared__ ull wbest[6];
    __shared__ ull win_sh;

    for (int r = 0; r < NS; ++r) {
        ull b = key;
#pragma unroll
        for (int m2 = 1; m2 < 64; m2 <<= 1) {
            ull o = __shfl_xor(b, m2, 64);
            b = (o > b) ? o : b;
        }
        if (lane == 0) wbest[wave] = b;
        __syncthreads();
        if (tid == 0) {
            ull m = wbest[0];
#pragma unroll
            for (int ww = 1; ww < 6; ++ww) m = (wbest[ww] > m) ? wbest[ww] : m;
            win_sh = m;
            sel[side * NS + r] = (int)(0xFFFFFFFFu - (unsigned)(m & 0xFFFFFFFFull));
        }
        __syncthreads();
        if (key == win_sh) key = 0ull;
    }
}

// ---------------- K3: gather + normalize + refinement (one wave per prototype) ----
// 640 threads = 10 waves. Gathers its 12 selected pixels from F, row-normalizes,
// writes normalized feats for k_tail, then runs 10 refinement iterations with
// prototype k resident in wave k's registers.
__global__ __launch_bounds__(640) void k_refine(const float* __restrict__ F,
                                                const int* __restrict__ sel,
                                                const float* __restrict__ fg,
                                                const float* __restrict__ bg,
                                                float* __restrict__ pfg,
                                                float* __restrict__ pbg,
                                                float* __restrict__ feats_out) {
    __shared__ float fe[NS * CC];
    __shared__ float dots[NS][KP];
    __shared__ int   assign[NS];

    const int tid  = threadIdx.x;
    const int k    = __builtin_amdgcn_readfirstlane(tid >> 6);   // wave id = proto id
    const int lane = tid & 63;
    const float* p0 = (blockIdx.x == 0) ? fg : bg;
    float* pout     = (blockIdx.x == 0) ? pfg : pbg;
    const int so    = blockIdx.x * NS;

    // gather 12 rows of 768 channels (stride-HW scattered reads)
    for (int i = tid; i < NS * CC; i += 640) {
        int srow = i / CC, c = i - srow * CC;
        int sp = sel[so + srow];
        int nn = sp >> 12, hh = sp & 4095;
        fe[i] = F[((size_t)nn * CC + c) * HW + hh];
    }
    float p[12];
#pragma unroll
    for (int j = 0; j < 12; ++j) p[j] = p0[k * CC + j * 64 + lane];
    __syncthreads();

    // row-normalize: wave k handles rows k, k+10
    for (int srow = k; srow < NS; srow += KP) {
        float ssq = 0.f;
#pragma unroll
        for (int j = 0; j < 12; ++j) { float v = fe[srow * CC + j * 64 + lane]; ssq = fmaf(v, v, ssq); }
#pragma unroll
        for (int m2 = 1; m2 < 64; m2 <<= 1) ssq += __shfl_xor(ssq, m2, 64);
        float inv = 1.f / fmaxf(sqrtf(ssq), 1e-8f);
#pragma unroll
        for (int j = 0; j < 12; ++j) fe[srow * CC + j * 64 + lane] *= inv;
    }
    __syncthreads();

    // publish normalized feats for k_tail (block0 -> rows 0..11, block1 -> 12..23)
    for (int i = tid; i < NS * CC; i += 640) feats_out[blockIdx.x * (NS * CC) + i] = fe[i];

    for (int it = 0; it < 10; ++it) {
        float step = 0.1f / (1.0f + 0.5f * (float)it);

        float d[NS];
#pragma unroll
        for (int s = 0; s < NS; ++s) d[s] = 0.f;
#pragma unroll
        for (int j = 0; j < 12; ++j) {
            float pvj = p[j];
#pragma unroll
            for (int s = 0; s < NS; ++s) d[s] = fmaf(fe[s * CC + j * 64 + lane], pvj, d[s]);
        }
#pragma unroll
        for (int s = 0; s < NS; ++s) {
#pragma unroll
            for (int m2 = 1; m2 < 64; m2 <<= 1) d[s] += __shfl_xor(d[s], m2, 64);
        }
        if (lane == 0) {
#pragma unroll
            for (int s = 0; s < NS; ++s) dots[s][k] = d[s];
        }
        __syncthreads();

        if (tid < NS) {
            float bv = dots[tid][0]; int bk = 0;
#pragma unroll
            for (int kk = 1; kk < KP; ++kk) { float v = dots[tid][kk]; if (v > bv) { bv = v; bk = kk; } }
            assign[tid] = bk;
        }
        __syncthreads();

        int a[NS]; int cnt = 0;
#pragma unroll
        for (int s = 0; s < NS; ++s) { a[s] = assign[s]; cnt += (a[s] == k) ? 1 : 0; }

        if (cnt > 0) {
            float mac[12];
#pragma unroll
            for (int j = 0; j < 12; ++j) mac[j] = 0.f;
#pragma unroll
            for (int s = 0; s < NS; ++s) {
                if (a[s] == k) {   // wave-uniform branch
#pragma unroll
                    for (int j = 0; j < 12; ++j) mac[j] += fe[s * CC + j * 64 + lane];
                }
            }
            float fcnt = (float)cnt;
            float v[12]; float ss = 0.f;
#pragma unroll
            for (int j = 0; j < 12; ++j) {
                float mean = mac[j] / fcnt;
                v[j] = (1.0f - step) * p[j] + step * mean;
                ss = fmaf(v[j], v[j], ss);
            }
#pragma unroll
            for (int m2 = 1; m2 < 64; m2 <<= 1) ss += __shfl_xor(ss, m2, 64);
            float inv = 1.f / fmaxf(sqrtf(ss), 1e-8f);
#pragma unroll
            for (int j = 0; j < 12; ++j) p[j] = v[j] * inv;
        }
    }

#pragma unroll
    for (int j = 0; j < 12; ++j) pout[k * CC + j * 64 + lane] = p[j];
}

// ---------------- K4: tail = blend (blocks 0..19) + loss (block 20) ----------------
__global__ __launch_bounds__(256) void k_tail(const float* __restrict__ feats,
                                              const float* __restrict__ fg,
                                              const float* __restrict__ bg,
                                              const float* __restrict__ pfg,
                                              const float* __restrict__ pbg,
                                              float* __restrict__ out) {
    const int r = blockIdx.x, tid = threadIdx.x;

    if (r < 20) {
        __shared__ float red[256];
        const float* a = (r < 10) ? (fg + r * CC) : (bg + (r - 10) * CC);
        const float* b = (r < 10) ? (pfg + r * CC) : (pbg + (r - 10) * CC);
        float v[3]; float ss = 0.f;
#pragma unroll
        for (int cc = 0; cc < 3; ++cc) {
            int c = tid + cc * 256;
            v[cc] = (1.0f - 0.3f) * a[c] + 0.3f * b[c];
            ss += v[cc] * v[cc];
        }
        red[tid] = ss; __syncthreads();
        for (int off = 128; off > 0; off >>= 1) { if (tid < off) red[tid] += red[tid + off]; __syncthreads(); }
        float inv = 1.f / fmaxf(sqrtf(red[0]), 1e-8f);
        float* o = out + 1 + r * CC;
#pragma unroll
        for (int cc = 0; cc < 3; ++cc) o[tid + cc * 256] = v[cc] * inv;
        return;
    }

    // ---- loss block ----
    __shared__ float dots3[NS * 30];   // [s][g*10+k]: g=0 pos@pfg, g=1 neg@pfg, g=2 pos@pbg
    __shared__ float mp[NS], mn[NS], infon[NS];
    int wave = tid >> 6, lane = tid & 63;

    for (int pid = wave; pid < 360; pid += 4) {
        int g = pid / 120, rr = pid % 120, s = rr / KP, k = rr % KP;
        const float4* a4 = (const float4*)(feats + ((g == 1 ? NS + s : s) * CC) + lane * 12);
        const float4* b4 = (const float4*)((g == 2 ? pbg : pfg) + k * CC + lane * 12);
        float acc = 0.f;
#pragma unroll
        for (int j = 0; j < 3; ++j) {
            float4 a = a4[j], b = b4[j];
            acc += a.x * b.x + a.y * b.y + a.z * b.z + a.w * b.w;
        }
#pragma unroll
        for (int m2 = 1; m2 < 64; m2 <<= 1) acc += __shfl_xor(acc, m2, 64);
        if (lane == 0) dots3[s * 30 + g * 10 + k] = acc;
    }
    __syncthreads();

    if (tid < NS) {
        const float* d = &dots3[tid * 30];
        float maxp = d[0], maxn = d[10];
#pragma unroll
        for (int k = 1; k < KP; ++k) { maxp = fmaxf(maxp, d[k]); maxn = fmaxf(maxn, d[10 + k]); }
        mp[tid] = maxp; mn[tid] = maxn;

        float x[KP], y[KP];
#pragma unroll
        for (int k = 0; k < KP; ++k) { x[k] = d[k] / 0.07f; y[k] = d[20 + k] / 0.07f; }
        float m10 = x[0];
#pragma unroll
        for (int k = 1; k < KP; ++k) m10 = fmaxf(m10, x[k]);
        float se = 0.f;
#pragma unroll
        for (int k = 0; k < KP; ++k) se += expf(x[k] - m10);
        float numer = logf(se) + m10;
        float m20 = m10;
#pragma unroll
        for (int k = 0; k < KP; ++k) m20 = fmaxf(m20, y[k]);
        float se2 = 0.f;
#pragma unroll
        for (int k = 0; k < KP; ++k) se2 += expf(x[k] - m20);
#pragma unroll
        for (int k = 0; k < KP; ++k) se2 += expf(y[k] - m20);
        float denom = logf(se2) + m20;
        infon[tid] = numer - denom;
    }
    __syncthreads();
    if (tid == 0) {
        float sp = 0.f, sn = 0.f, si = 0.f;
        for (int s = 0; s < NS; ++s) { sp += mp[s]; sn += mn[s]; si += infon[s]; }
        sp /= 12.f; sn /= 12.f; si /= 12.f;
        float loss = fmaxf(0.2f + sn - sp, 0.f) + 0.25f * (-si);
        out[0] = loss;
    }
}

extern "C" void kernel_launch(void* const* d_in, const int* in_sizes, int n_in,
                              void* d_out, int out_size, void* d_ws, size_t ws_size,
                              hipStream_t stream) {
    const float* fg = (const float*)d_in[0];   // [10,768]
    const float* bg = (const float*)d_in[1];   // [10,768]
    const float* F  = (const float*)d_in[2];   // [8,768,64,64]
    const float* M  = (const float*)d_in[3];   // [8,1,64,64]
    float* out = (float*)d_out;                // [1 + 7680 + 7680]

    float* w    = (float*)d_ws;
    int*   sel  = (int*)(w + WS_SEL);
    float* fea  = w + WS_FEATS;
    float* pfg  = w + WS_PFG;
    float* pbg  = w + WS_PBG;
    ull*   cand = (ull*)(w + WS_CAND);   // overlaps pfg; consumed before refine writes

    k_scores<<<512, 512, 0, stream>>>(fg, bg, F, M, w + WS_SCORE_FG, w + WS_SCORE_BG);
    k_topk1 <<<64, 256, 0, stream>>>(w, cand);
    k_topk2 <<<2, 384, 0, stream>>>(cand, sel);
    k_refine<<<2, 640, 0, stream>>>(F, sel, fg, bg, pfg, pbg, fea);
    k_tail  <<<21, 256, 0, stream>>>(fea, fg, bg, pfg, pbg, out);
}

// Round 7
// 187.966 us; speedup vs baseline: 1.0090x; 1.0090x over previous
//
#include <hip/hip_runtime.h>
#include <math.h>

// Problem constants
#define KP   10      // prototypes per side
#define CC   768     // channels
#define NB   8       // batch
#define HW   4096    // 64*64
#define STOT 32768   // NB*HW
#define NS   12      // N_SAMPLES

// Workspace layout (float offsets)
#define WS_SCORE_FG 0
#define WS_SCORE_BG 32768
#define WS_SEL      65536   // 24 ints
#define WS_FEATS    65600   // 24*768 floats (pos 12 rows, then neg 12 rows)
#define WS_PFG      84032   // 10*768
#define WS_PBG      91712   // 10*768
// top-k candidates (2 sides x 384 u64) overlap WS_PFG: written by k_topk1,
// read by k_topk2, and only later clobbered by k_refine's pfg output. Safe.
#define WS_CAND     84032

typedef unsigned long long ull;

// ---------------- K1: per-pixel norm + max-sim scores ----------------
// 1024-thread blocks: 16 waves x 64 pixels; wave w covers channels
// [48w, 48w+48). 512 blocks x 16 waves = 8 waves/SIMD (HW max occupancy).
// F streamed non-temporally + 1-round prefetch; protos via uniform-address
// vector float4 loads. Two-stage LDS partial reduction keeps LDS at 50 KB
// so 2 blocks/CU co-reside.
__global__ __launch_bounds__(1024, 2) void k_scores(const float* __restrict__ fg,
                                                    const float* __restrict__ bg,
                                                    const float* __restrict__ F,
                                                    const float* __restrict__ M,
                                                    float* __restrict__ sfg,
                                                    float* __restrict__ sbg) {
    __shared__ float part[8][64][22];
    __shared__ float comb[64][22];

    const int tid  = threadIdx.x;
    const int w    = __builtin_amdgcn_readfirstlane(tid >> 6);  // wave id 0..15
    const int lane = tid & 63;
    const int s    = blockIdx.x * 64 + lane;
    const int n    = s >> 12, hw = s & 4095;
    const float* fp = F + ((size_t)n * CC) * HW + hw;
    const int cbase = w * 48;

    int z;  // opaque zero in a VGPR: keeps proto addresses on the vector path
    asm volatile("v_mov_b32 %0, 0" : "=v"(z));
    const float* fgz = fg + z;
    const float* bgz = bg + z;

    float afg[KP], abg[KP], norm2 = 0.f;
#pragma unroll
    for (int k = 0; k < KP; ++k) { afg[k] = 0.f; abg[k] = 0.f; }

    float fn[8];
#pragma unroll
    for (int j = 0; j < 8; ++j) fn[j] = __builtin_nontemporal_load(fp + (size_t)(cbase + j) * HW);

    for (int c0 = 0; c0 < 48; c0 += 8) {
        float f[8];
#pragma unroll
        for (int j = 0; j < 8; ++j) f[j] = fn[j];
        if (c0 + 8 < 48) {
#pragma unroll
            for (int j = 0; j < 8; ++j)
                fn[j] = __builtin_nontemporal_load(fp + (size_t)(cbase + c0 + 8 + j) * HW);
        }

#pragma unroll
        for (int k = 0; k < KP; ++k) {
            const float4* pq = (const float4*)(fgz + k * CC + cbase + c0);
            float4 a = pq[0], b = pq[1];
            float acc = afg[k];
            acc = fmaf(f[0], a.x, acc); acc = fmaf(f[1], a.y, acc);
            acc = fmaf(f[2], a.z, acc); acc = fmaf(f[3], a.w, acc);
            acc = fmaf(f[4], b.x, acc); acc = fmaf(f[5], b.y, acc);
            acc = fmaf(f[6], b.z, acc); acc = fmaf(f[7], b.w, acc);
            afg[k] = acc;
        }
#pragma unroll
        for (int k = 0; k < KP; ++k) {
            const float4* pq = (const float4*)(bgz + k * CC + cbase + c0);
            float4 a = pq[0], b = pq[1];
            float acc = abg[k];
            acc = fmaf(f[0], a.x, acc); acc = fmaf(f[1], a.y, acc);
            acc = fmaf(f[2], a.z, acc); acc = fmaf(f[3], a.w, acc);
            acc = fmaf(f[4], b.x, acc); acc = fmaf(f[5], b.y, acc);
            acc = fmaf(f[6], b.z, acc); acc = fmaf(f[7], b.w, acc);
            abg[k] = acc;
        }
#pragma unroll
        for (int j = 0; j < 8; ++j) norm2 = fmaf(f[j], f[j], norm2);
    }

    // two-stage partial fold: waves 8..15 write, waves 0..7 accumulate in place
    if (w >= 8) {
#pragma unroll
        for (int k = 0; k < KP; ++k) { part[w - 8][lane][k] = afg[k]; part[w - 8][lane][10 + k] = abg[k]; }
        part[w - 8][lane][20] = norm2;
    }
    __syncthreads();
    if (w < 8) {
#pragma unroll
        for (int k = 0; k < KP; ++k) {
            part[w][lane][k]      += afg[k];
            part[w][lane][10 + k] += abg[k];
        }
        part[w][lane][20] += norm2;
    }
    __syncthreads();

    // reduce 8 sub-partials -> comb[pix][j], 64*21 = 1344 items over 1024 threads
    for (int item = tid; item < 64 * 21; item += 1024) {
        int pix = item / 21, j = item - pix * 21;
        float acc = 0.f;
#pragma unroll
        for (int ww = 0; ww < 8; ++ww) acc += part[ww][pix][j];
        comb[pix][j] = acc;
    }
    __syncthreads();

    if (tid < 64) {
        float mfg = comb[tid][0], mbg = comb[tid][10];
#pragma unroll
        for (int k = 1; k < KP; ++k) { mfg = fmaxf(mfg, comb[tid][k]); mbg = fmaxf(mbg, comb[tid][10 + k]); }
        float nc = fmaxf(sqrtf(comb[tid][20]), 1e-8f);
        int sp = blockIdx.x * 64 + tid;
        float m = fminf(fmaxf(M[sp], 0.f), 1.f);
        sfg[sp] = (1.f - mfg / nc) * m;
        sbg[sp] = (1.f - mbg / nc) * (1.f - m);
    }
}

// Order-preserving float->uint map, packed with ~index for exact
// (value desc, index asc) ordering under unsigned max.
__device__ __forceinline__ ull pack_key(float v, int idx) {
    unsigned u = __float_as_uint(v);
    u ^= (unsigned)((int)u >> 31) | 0x80000000u;
    return ((ull)u << 32) | (ull)(0xFFFFFFFFu - (unsigned)idx);
}

// ---------------- K2a: top-12 stage 1 (64 blocks: 32 per side) ----------------
__global__ __launch_bounds__(256) void k_topk1(const float* __restrict__ ws,
                                               ull* __restrict__ cand) {
    const int side = blockIdx.x >> 5, blk = blockIdx.x & 31;
    const float4* sc4 = (const float4*)(ws + (side == 0 ? WS_SCORE_FG : WS_SCORE_BG));
    const int tid = threadIdx.x;
    const int wave = tid >> 6, lane = tid & 63;

    const int i4 = blk * 256 + tid;
    float4 v4 = sc4[i4];
    ull kk[4];
    kk[0] = pack_key(v4.x, 4 * i4 + 0);
    kk[1] = pack_key(v4.y, 4 * i4 + 1);
    kk[2] = pack_key(v4.z, 4 * i4 + 2);
    kk[3] = pack_key(v4.w, 4 * i4 + 3);

    __shared__ ull wbest[4];
    __shared__ ull win_sh;

    for (int r = 0; r < NS; ++r) {
        ull b = kk[0];
#pragma unroll
        for (int q = 1; q < 4; ++q) b = (kk[q] > b) ? kk[q] : b;
#pragma unroll
        for (int m2 = 1; m2 < 64; m2 <<= 1) {
            ull o = __shfl_xor(b, m2, 64);
            b = (o > b) ? o : b;
        }
        if (lane == 0) wbest[wave] = b;
        __syncthreads();
        if (tid == 0) {
            ull m = wbest[0];
#pragma unroll
            for (int ww = 1; ww < 4; ++ww) m = (wbest[ww] > m) ? wbest[ww] : m;
            win_sh = m;
            cand[side * 384 + blk * NS + r] = m;
        }
        __syncthreads();
        ull win = win_sh;
#pragma unroll
        for (int q = 0; q < 4; ++q) { if (kk[q] == win) kk[q] = 0ull; }
    }
}

// ---------------- K2b: top-12 stage 2 (merge 384 candidates per side) ----------------
__global__ __launch_bounds__(384) void k_topk2(const ull* __restrict__ cand,
                                               int* __restrict__ sel) {
    const int side = blockIdx.x;
    const int tid = threadIdx.x;
    const int wave = tid >> 6, lane = tid & 63;

    ull key = cand[side * 384 + tid];

    __shared__ ull wbest[6];
    __shared__ ull win_sh;

    for (int r = 0; r < NS; ++r) {
        ull b = key;
#pragma unroll
        for (int m2 = 1; m2 < 64; m2 <<= 1) {
            ull o = __shfl_xor(b, m2, 64);
            b = (o > b) ? o : b;
        }
        if (lane == 0) wbest[wave] = b;
        __syncthreads();
        if (tid == 0) {
            ull m = wbest[0];
#pragma unroll
            for (int ww = 1; ww < 6; ++ww) m = (wbest[ww] > m) ? wbest[ww] : m;
            win_sh = m;
            sel[side * NS + r] = (int)(0xFFFFFFFFu - (unsigned)(m & 0xFFFFFFFFull));
        }
        __syncthreads();
        if (key == win_sh) key = 0ull;
    }
}

// ---------------- K3: gather selected pixels + normalize ----------------
__global__ __launch_bounds__(256) void k_gather(const float* __restrict__ F,
                                                const int* __restrict__ sel,
                                                float* __restrict__ feats) {
    int b = blockIdx.x;                  // 0..23
    int s = sel[b];
    int n = s >> 12, hw = s & 4095;
    const float* fp = F + ((size_t)n * CC) * HW + hw;
    int tid = threadIdx.x;

    float v0 = fp[(size_t)(tid)       * HW];
    float v1 = fp[(size_t)(tid + 256) * HW];
    float v2 = fp[(size_t)(tid + 512) * HW];
    __shared__ float red[256];
    red[tid] = v0 * v0 + v1 * v1 + v2 * v2;
    __syncthreads();
    for (int off = 128; off > 0; off >>= 1) { if (tid < off) red[tid] += red[tid + off]; __syncthreads(); }
    float inv = 1.f / fmaxf(sqrtf(red[0]), 1e-8f);
    feats[b * CC + tid]       = v0 * inv;
    feats[b * CC + tid + 256] = v1 * inv;
    feats[b * CC + tid + 512] = v2 * inv;
}

// ---------------- K4: refinement, one wave per prototype ----------------
__global__ __launch_bounds__(640) void k_refine(const float* __restrict__ feats_all,
                                                const float* __restrict__ fg,
                                                const float* __restrict__ bg,
                                                float* __restrict__ pfg,
                                                float* __restrict__ pbg) {
    __shared__ float fe[NS * CC];
    __shared__ float dots[NS][KP];
    __shared__ int   assign[NS];

    const int tid  = threadIdx.x;
    const int k    = __builtin_amdgcn_readfirstlane(tid >> 6);   // wave id = proto id
    const int lane = tid & 63;
    const float* feats = feats_all + blockIdx.x * (NS * CC);
    const float* p0    = (blockIdx.x == 0) ? fg : bg;
    float* pout        = (blockIdx.x == 0) ? pfg : pbg;

    for (int i = tid; i < NS * CC; i += 640) fe[i] = feats[i];
    float p[12];
#pragma unroll
    for (int j = 0; j < 12; ++j) p[j] = p0[k * CC + j * 64 + lane];
    __syncthreads();

    for (int it = 0; it < 10; ++it) {
        float step = 0.1f / (1.0f + 0.5f * (float)it);

        float d[NS];
#pragma unroll
        for (int s = 0; s < NS; ++s) d[s] = 0.f;
#pragma unroll
        for (int j = 0; j < 12; ++j) {
            float pvj = p[j];
#pragma unroll
            for (int s = 0; s < NS; ++s) d[s] = fmaf(fe[s * CC + j * 64 + lane], pvj, d[s]);
        }
#pragma unroll
        for (int s = 0; s < NS; ++s) {
#pragma unroll
            for (int m2 = 1; m2 < 64; m2 <<= 1) d[s] += __shfl_xor(d[s], m2, 64);
        }
        if (lane == 0) {
#pragma unroll
            for (int s = 0; s < NS; ++s) dots[s][k] = d[s];
        }
        __syncthreads();

        if (tid < NS) {
            float bv = dots[tid][0]; int bk = 0;
#pragma unroll
            for (int kk = 1; kk < KP; ++kk) { float v = dots[tid][kk]; if (v > bv) { bv = v; bk = kk; } }
            assign[tid] = bk;
        }
        __syncthreads();

        int a[NS]; int cnt = 0;
#pragma unroll
        for (int s = 0; s < NS; ++s) { a[s] = assign[s]; cnt += (a[s] == k) ? 1 : 0; }

        if (cnt > 0) {
            float mac[12];
#pragma unroll
            for (int j = 0; j < 12; ++j) mac[j] = 0.f;
#pragma unroll
            for (int s = 0; s < NS; ++s) {
                if (a[s] == k) {   // wave-uniform branch
#pragma unroll
                    for (int j = 0; j < 12; ++j) mac[j] += fe[s * CC + j * 64 + lane];
                }
            }
            float fcnt = (float)cnt;
            float v[12]; float ss = 0.f;
#pragma unroll
            for (int j = 0; j < 12; ++j) {
                float mean = mac[j] / fcnt;
                v[j] = (1.0f - step) * p[j] + step * mean;
                ss = fmaf(v[j], v[j], ss);
            }
#pragma unroll
            for (int m2 = 1; m2 < 64; m2 <<= 1) ss += __shfl_xor(ss, m2, 64);
            float inv = 1.f / fmaxf(sqrtf(ss), 1e-8f);
#pragma unroll
            for (int j = 0; j < 12; ++j) p[j] = v[j] * inv;
        }
    }

#pragma unroll
    for (int j = 0; j < 12; ++j) pout[k * CC + j * 64 + lane] = p[j];
}

// ---------------- K5: tail = blend (blocks 0..19) + loss (block 20) ----------------
__global__ __launch_bounds__(256) void k_tail(const float* __restrict__ feats,
                                              const float* __restrict__ fg,
                                              const float* __restrict__ bg,
                                              const float* __restrict__ pfg,
                                              const float* __restrict__ pbg,
                                              float* __restrict__ out) {
    const int r = blockIdx.x, tid = threadIdx.x;

    if (r < 20) {
        __shared__ float red[256];
        const float* a = (r < 10) ? (fg + r * CC) : (bg + (r - 10) * CC);
        const float* b = (r < 10) ? (pfg + r * CC) : (pbg + (r - 10) * CC);
        float v[3]; float ss = 0.f;
#pragma unroll
        for (int cc = 0; cc < 3; ++cc) {
            int c = tid + cc * 256;
            v[cc] = (1.0f - 0.3f) * a[c] + 0.3f * b[c];
            ss += v[cc] * v[cc];
        }
        red[tid] = ss; __syncthreads();
        for (int off = 128; off > 0; off >>= 1) { if (tid < off) red[tid] += red[tid + off]; __syncthreads(); }
        float inv = 1.f / fmaxf(sqrtf(red[0]), 1e-8f);
        float* o = out + 1 + r * CC;
#pragma unroll
        for (int cc = 0; cc < 3; ++cc) o[tid + cc * 256] = v[cc] * inv;
        return;
    }

    // ---- loss block ----
    __shared__ float dots3[NS * 30];   // [s][g*10+k]: g=0 pos@pfg, g=1 neg@pfg, g=2 pos@pbg
    __shared__ float mp[NS], mn[NS], infon[NS];
    int wave = tid >> 6, lane = tid & 63;

    for (int pid = wave; pid < 360; pid += 4) {
        int g = pid / 120, rr = pid % 120, s = rr / KP, k = rr % KP;
        const float4* a4 = (const float4*)(feats + ((g == 1 ? NS + s : s) * CC) + lane * 12);
        const float4* b4 = (const float4*)((g == 2 ? pbg : pfg) + k * CC + lane * 12);
        float acc = 0.f;
#pragma unroll
        for (int j = 0; j < 3; ++j) {
            float4 a = a4[j], b = b4[j];
            acc += a.x * b.x + a.y * b.y + a.z * b.z + a.w * b.w;
        }
#pragma unroll
        for (int m2 = 1; m2 < 64; m2 <<= 1) acc += __shfl_xor(acc, m2, 64);
        if (lane == 0) dots3[s * 30 + g * 10 + k] = acc;
    }
    __syncthreads();

    if (tid < NS) {
        const float* d = &dots3[tid * 30];
        float maxp = d[0], maxn = d[10];
#pragma unroll
        for (int k = 1; k < KP; ++k) { maxp = fmaxf(maxp, d[k]); maxn = fmaxf(maxn, d[10 + k]); }
        mp[tid] = maxp; mn[tid] = maxn;

        float x[KP], y[KP];
#pragma unroll
        for (int k = 0; k < KP; ++k) { x[k] = d[k] / 0.07f; y[k] = d[20 + k] / 0.07f; }
        float m10 = x[0];
#pragma unroll
        for (int k = 1; k < KP; ++k) m10 = fmaxf(m10, x[k]);
        float se = 0.f;
#pragma unroll
        for (int k = 0; k < KP; ++k) se += expf(x[k] - m10);
        float numer = logf(se) + m10;
        float m20 = m10;
#pragma unroll
        for (int k = 0; k < KP; ++k) m20 = fmaxf(m20, y[k]);
        float se2 = 0.f;
#pragma unroll
        for (int k = 0; k < KP; ++k) se2 += expf(x[k] - m20);
#pragma unroll
        for (int k = 0; k < KP; ++k) se2 += expf(y[k] - m20);
        float denom = logf(se2) + m20;
        infon[tid] = numer - denom;
    }
    __syncthreads();
    if (tid == 0) {
        float sp = 0.f, sn = 0.f, si = 0.f;
        for (int s = 0; s < NS; ++s) { sp += mp[s]; sn += mn[s]; si += infon[s]; }
        sp /= 12.f; sn /= 12.f; si /= 12.f;
        float loss = fmaxf(0.2f + sn - sp, 0.f) + 0.25f * (-si);
        out[0] = loss;
    }
}

extern "C" void kernel_launch(void* const* d_in, const int* in_sizes, int n_in,
                              void* d_out, int out_size, void* d_ws, size_t ws_size,
                              hipStream_t stream) {
    const float* fg = (const float*)d_in[0];   // [10,768]
    const float* bg = (const float*)d_in[1];   // [10,768]
    const float* F  = (const float*)d_in[2];   // [8,768,64,64]
    const float* M  = (const float*)d_in[3];   // [8,1,64,64]
    float* out = (float*)d_out;                // [1 + 7680 + 7680]

    float* w    = (float*)d_ws;
    int*   sel  = (int*)(w + WS_SEL);
    float* fea  = w + WS_FEATS;
    float* pfg  = w + WS_PFG;
    float* pbg  = w + WS_PBG;
    ull*   cand = (ull*)(w + WS_CAND);   // overlaps pfg; consumed before refine writes

    k_scores<<<512, 1024, 0, stream>>>(fg, bg, F, M, w + WS_SCORE_FG, w + WS_SCORE_BG);
    k_topk1 <<<64, 256, 0, stream>>>(w, cand);
    k_topk2 <<<2, 384, 0, stream>>>(cand, sel);
    k_gather<<<24, 256, 0, stream>>>(F, sel, fea);
    k_refine<<<2, 640, 0, stream>>>(fea, fg, bg, pfg, pbg);
    k_tail  <<<21, 256, 0, stream>>>(fea, fg, bg, pfg, pbg, out);
}

// Round 9
// 173.401 us; speedup vs baseline: 1.0938x; 1.0840x over previous
//
#include <hip/hip_runtime.h>
#include <math.h>

// Problem constants
#define KP   10      // prototypes per side
#define CC   768     // channels
#define NB   8       // batch
#define HW   4096    // 64*64
#define STOT 32768   // NB*HW
#define NS   12      // N_SAMPLES

// Workspace layout (float offsets)
#define WS_SCORE_FG 0
#define WS_SCORE_BG 32768
#define WS_SEL      65536   // 24 ints
#define WS_FEATS    65600   // 24*768 floats (pos 12 rows, then neg 12 rows)
#define WS_PFG      84032   // 10*768
#define WS_PBG      91712   // 10*768
// top-k candidates (2 sides x 384 u64) overlap WS_PFG: written by k_topk1,
// read by k_topk2, and only later clobbered by k_refine's pfg output. Safe.
#define WS_CAND     84032

typedef unsigned long long ull;
typedef float f2v __attribute__((ext_vector_type(2)));   // clang vector: OK for nontemporal builtin

// ---------------- K1: per-pixel norm + max-sim scores ----------------
// 512-thread blocks: 8 waves x 96 channels each; 2 pixels PER LANE (dwordx2
// F loads). 256 blocks x 128 px. Halves per-CU VMEM instruction count vs R7
// (proto loads amortize over 2 px). F non-temporal + 1-round prefetch;
// protos via uniform-address vector float4 loads (z-trick).
__global__ __launch_bounds__(512) void k_scores(const float* __restrict__ fg,
                                                const float* __restrict__ bg,
                                                const float* __restrict__ F,
                                                const float* __restrict__ M,
                                                float* __restrict__ sfg,
                                                float* __restrict__ sbg) {
    __shared__ float part[4][64][2][21];   // 42 KB

    const int tid  = threadIdx.x;
    const int w    = __builtin_amdgcn_readfirstlane(tid >> 6);  // wave id 0..7
    const int lane = tid & 63;
    const int b    = blockIdx.x;            // 0..255
    const int n    = b >> 5;                // 32 blocks per image
    const int hwb  = (b & 31) * 128 + lane * 2;
    const float* fp = F + ((size_t)n * CC) * HW + hwb;
    const int cbase = w * 96;

    int z;  // opaque zero in a VGPR: keeps proto addresses on the vector path
    asm volatile("v_mov_b32 %0, 0" : "=v"(z));
    const float* fgz = fg + z;
    const float* bgz = bg + z;

    float afg[2][KP], abg[2][KP], n2[2];
#pragma unroll
    for (int k = 0; k < KP; ++k) { afg[0][k] = 0.f; afg[1][k] = 0.f; abg[0][k] = 0.f; abg[1][k] = 0.f; }
    n2[0] = 0.f; n2[1] = 0.f;

    f2v fn[8];
#pragma unroll
    for (int j = 0; j < 8; ++j)
        fn[j] = __builtin_nontemporal_load((const f2v*)(fp + (size_t)(cbase + j) * HW));

    for (int c0 = 0; c0 < 96; c0 += 8) {
        f2v f[8];
#pragma unroll
        for (int j = 0; j < 8; ++j) f[j] = fn[j];
        if (c0 + 8 < 96) {
#pragma unroll
            for (int j = 0; j < 8; ++j)
                fn[j] = __builtin_nontemporal_load((const f2v*)(fp + (size_t)(cbase + c0 + 8 + j) * HW));
        }

#pragma unroll
        for (int k = 0; k < KP; ++k) {
            const float4* pq = (const float4*)(fgz + k * CC + cbase + c0);
            float4 a = pq[0], c = pq[1];
            float acc0 = afg[0][k], acc1 = afg[1][k];
            acc0 = fmaf(f[0].x, a.x, acc0); acc1 = fmaf(f[0].y, a.x, acc1);
            acc0 = fmaf(f[1].x, a.y, acc0); acc1 = fmaf(f[1].y, a.y, acc1);
            acc0 = fmaf(f[2].x, a.z, acc0); acc1 = fmaf(f[2].y, a.z, acc1);
            acc0 = fmaf(f[3].x, a.w, acc0); acc1 = fmaf(f[3].y, a.w, acc1);
            acc0 = fmaf(f[4].x, c.x, acc0); acc1 = fmaf(f[4].y, c.x, acc1);
            acc0 = fmaf(f[5].x, c.y, acc0); acc1 = fmaf(f[5].y, c.y, acc1);
            acc0 = fmaf(f[6].x, c.z, acc0); acc1 = fmaf(f[6].y, c.z, acc1);
            acc0 = fmaf(f[7].x, c.w, acc0); acc1 = fmaf(f[7].y, c.w, acc1);
            afg[0][k] = acc0; afg[1][k] = acc1;
        }
#pragma unroll
        for (int k = 0; k < KP; ++k) {
            const float4* pq = (const float4*)(bgz + k * CC + cbase + c0);
            float4 a = pq[0], c = pq[1];
            float acc0 = abg[0][k], acc1 = abg[1][k];
            acc0 = fmaf(f[0].x, a.x, acc0); acc1 = fmaf(f[0].y, a.x, acc1);
            acc0 = fmaf(f[1].x, a.y, acc0); acc1 = fmaf(f[1].y, a.y, acc1);
            acc0 = fmaf(f[2].x, a.z, acc0); acc1 = fmaf(f[2].y, a.z, acc1);
            acc0 = fmaf(f[3].x, a.w, acc0); acc1 = fmaf(f[3].y, a.w, acc1);
            acc0 = fmaf(f[4].x, c.x, acc0); acc1 = fmaf(f[4].y, c.x, acc1);
            acc0 = fmaf(f[5].x, c.y, acc0); acc1 = fmaf(f[5].y, c.y, acc1);
            acc0 = fmaf(f[6].x, c.z, acc0); acc1 = fmaf(f[6].y, c.z, acc1);
            acc0 = fmaf(f[7].x, c.w, acc0); acc1 = fmaf(f[7].y, c.w, acc1);
            abg[0][k] = acc0; abg[1][k] = acc1;
        }
#pragma unroll
        for (int j = 0; j < 8; ++j) {
            n2[0] = fmaf(f[j].x, f[j].x, n2[0]);
            n2[1] = fmaf(f[j].y, f[j].y, n2[1]);
        }
    }

    // fold 8 waves -> 4 slots: waves 4..7 write, waves 0..3 add in place
    if (w >= 4) {
#pragma unroll
        for (int px = 0; px < 2; ++px) {
#pragma unroll
            for (int k = 0; k < KP; ++k) {
                part[w - 4][lane][px][k]      = afg[px][k];
                part[w - 4][lane][px][10 + k] = abg[px][k];
            }
            part[w - 4][lane][px][20] = n2[px];
        }
    }
    __syncthreads();
    if (w < 4) {
#pragma unroll
        for (int px = 0; px < 2; ++px) {
#pragma unroll
            for (int k = 0; k < KP; ++k) {
                part[w][lane][px][k]      += afg[px][k];
                part[w][lane][px][10 + k] += abg[px][k];
            }
            part[w][lane][px][20] += n2[px];
        }
    }
    __syncthreads();

    // final: threads 0..127 -> (lane2, j) ; px = b*128 + tid (coalesced)
    if (tid < 128) {
        const int lane2 = tid >> 1, j = tid & 1;
        float vals[21];
#pragma unroll
        for (int q = 0; q < 21; ++q) {
            float acc = 0.f;
#pragma unroll
            for (int ss = 0; ss < 4; ++ss) acc += part[ss][lane2][j][q];
            vals[q] = acc;
        }
        float mfg = vals[0], mbg = vals[10];
#pragma unroll
        for (int k = 1; k < KP; ++k) { mfg = fmaxf(mfg, vals[k]); mbg = fmaxf(mbg, vals[10 + k]); }
        float nc = fmaxf(sqrtf(vals[20]), 1e-8f);
        int sp = b * 128 + tid;
        float m = fminf(fmaxf(M[sp], 0.f), 1.f);
        sfg[sp] = (1.f - mfg / nc) * m;
        sbg[sp] = (1.f - mbg / nc) * (1.f - m);
    }
}

// Order-preserving float->uint map, packed with ~index for exact
// (value desc, index asc) ordering under unsigned max.
__device__ __forceinline__ ull pack_key(float v, int idx) {
    unsigned u = __float_as_uint(v);
    u ^= (unsigned)((int)u >> 31) | 0x80000000u;
    return ((ull)u << 32) | (ull)(0xFFFFFFFFu - (unsigned)idx);
}

// ---------------- K2a: top-12 stage 1 (64 blocks: 32 per side) ----------------
__global__ __launch_bounds__(256) void k_topk1(const float* __restrict__ ws,
                                               ull* __restrict__ cand) {
    const int side = blockIdx.x >> 5, blk = blockIdx.x & 31;
    const float4* sc4 = (const float4*)(ws + (side == 0 ? WS_SCORE_FG : WS_SCORE_BG));
    const int tid = threadIdx.x;
    const int wave = tid >> 6, lane = tid & 63;

    const int i4 = blk * 256 + tid;
    float4 v4 = sc4[i4];
    ull kk[4];
    kk[0] = pack_key(v4.x, 4 * i4 + 0);
    kk[1] = pack_key(v4.y, 4 * i4 + 1);
    kk[2] = pack_key(v4.z, 4 * i4 + 2);
    kk[3] = pack_key(v4.w, 4 * i4 + 3);

    __shared__ ull wbest[4];
    __shared__ ull win_sh;

    for (int r = 0; r < NS; ++r) {
        ull b = kk[0];
#pragma unroll
        for (int q = 1; q < 4; ++q) b = (kk[q] > b) ? kk[q] : b;
#pragma unroll
        for (int m2 = 1; m2 < 64; m2 <<= 1) {
            ull o = __shfl_xor(b, m2, 64);
            b = (o > b) ? o : b;
        }
        if (lane == 0) wbest[wave] = b;
        __syncthreads();
        if (tid == 0) {
            ull m = wbest[0];
#pragma unroll
            for (int ww = 1; ww < 4; ++ww) m = (wbest[ww] > m) ? wbest[ww] : m;
            win_sh = m;
            cand[side * 384 + blk * NS + r] = m;
        }
        __syncthreads();
        ull win = win_sh;
#pragma unroll
        for (int q = 0; q < 4; ++q) { if (kk[q] == win) kk[q] = 0ull; }
    }
}

// ---------------- K2b: top-12 stage 2 (merge 384 candidates per side) ----------------
__global__ __launch_bounds__(384) void k_topk2(const ull* __restrict__ cand,
                                               int* __restrict__ sel) {
    const int side = blockIdx.x;
    const int tid = threadIdx.x;
    const int wave = tid >> 6, lane = tid & 63;

    ull key = cand[side * 384 + tid];

    __shared__ ull wbest[6];
    __shared__ ull win_sh;

    for (int r = 0; r < NS; ++r) {
        ull b = key;
#pragma unroll
        for (int m2 = 1; m2 < 64; m2 <<= 1) {
            ull o = __shfl_xor(b, m2, 64);
            b = (o > b) ? o : b;
        }
        if (lane == 0) wbest[wave] = b;
        __syncthreads();
        if (tid == 0) {
            ull m = wbest[0];
#pragma unroll
            for (int ww = 1; ww < 6; ++ww) m = (wbest[ww] > m) ? wbest[ww] : m;
            win_sh = m;
            sel[side * NS + r] = (int)(0xFFFFFFFFu - (unsigned)(m & 0xFFFFFFFFull));
        }
        __syncthreads();
        if (key == win_sh) key = 0ull;
    }
}

// ---------------- K3: gather selected pixels + normalize ----------------
__global__ __launch_bounds__(256) void k_gather(const float* __restrict__ F,
                                                const int* __restrict__ sel,
                                                float* __restrict__ feats) {
    int b = blockIdx.x;                  // 0..23
    int s = sel[b];
    int n = s >> 12, hw = s & 4095;
    const float* fp = F + ((size_t)n * CC) * HW + hw;
    int tid = threadIdx.x;

    float v0 = fp[(size_t)(tid)       * HW];
    float v1 = fp[(size_t)(tid + 256) * HW];
    float v2 = fp[(size_t)(tid + 512) * HW];
    __shared__ float red[256];
    red[tid] = v0 * v0 + v1 * v1 + v2 * v2;
    __syncthreads();
    for (int off = 128; off > 0; off >>= 1) { if (tid < off) red[tid] += red[tid + off]; __syncthreads(); }
    float inv = 1.f / fmaxf(sqrtf(red[0]), 1e-8f);
    feats[b * CC + tid]       = v0 * inv;
    feats[b * CC + tid + 256] = v1 * inv;
    feats[b * CC + tid + 512] = v2 * inv;
}

// ---------------- K4: refinement, one wave per prototype ----------------
__global__ __launch_bounds__(640) void k_refine(const float* __restrict__ feats_all,
                                                const float* __restrict__ fg,
                                                const float* __restrict__ bg,
                                                float* __restrict__ pfg,
                                                float* __restrict__ pbg) {
    __shared__ float fe[NS * CC];
    __shared__ float dots[NS][KP];
    __shared__ int   assign[NS];

    const int tid  = threadIdx.x;
    const int k    = __builtin_amdgcn_readfirstlane(tid >> 6);   // wave id = proto id
    const int lane = tid & 63;
    const float* feats = feats_all + blockIdx.x * (NS * CC);
    const float* p0    = (blockIdx.x == 0) ? fg : bg;
    float* pout        = (blockIdx.x == 0) ? pfg : pbg;

    for (int i = tid; i < NS * CC; i += 640) fe[i] = feats[i];
    float p[12];
#pragma unroll
    for (int j = 0; j < 12; ++j) p[j] = p0[k * CC + j * 64 + lane];
    __syncthreads();

    for (int it = 0; it < 10; ++it) {
        float step = 0.1f / (1.0f + 0.5f * (float)it);

        float d[NS];
#pragma unroll
        for (int s = 0; s < NS; ++s) d[s] = 0.f;
#pragma unroll
        for (int j = 0; j < 12; ++j) {
            float pvj = p[j];
#pragma unroll
            for (int s = 0; s < NS; ++s) d[s] = fmaf(fe[s * CC + j * 64 + lane], pvj, d[s]);
        }
#pragma unroll
        for (int s = 0; s < NS; ++s) {
#pragma unroll
            for (int m2 = 1; m2 < 64; m2 <<= 1) d[s] += __shfl_xor(d[s], m2, 64);
        }
        if (lane == 0) {
#pragma unroll
            for (int s = 0; s < NS; ++s) dots[s][k] = d[s];
        }
        __syncthreads();

        if (tid < NS) {
            float bv = dots[tid][0]; int bk = 0;
#pragma unroll
            for (int kk = 1; kk < KP; ++kk) { float v = dots[tid][kk]; if (v > bv) { bv = v; bk = kk; } }
            assign[tid] = bk;
        }
        __syncthreads();

        int a[NS]; int cnt = 0;
#pragma unroll
        for (int s = 0; s < NS; ++s) { a[s] = assign[s]; cnt += (a[s] == k) ? 1 : 0; }

        if (cnt > 0) {
            float mac[12];
#pragma unroll
            for (int j = 0; j < 12; ++j) mac[j] = 0.f;
#pragma unroll
            for (int s = 0; s < NS; ++s) {
                if (a[s] == k) {   // wave-uniform branch
#pragma unroll
                    for (int j = 0; j < 12; ++j) mac[j] += fe[s * CC + j * 64 + lane];
                }
            }
            float fcnt = (float)cnt;
            float v[12]; float ss = 0.f;
#pragma unroll
            for (int j = 0; j < 12; ++j) {
                float mean = mac[j] / fcnt;
                v[j] = (1.0f - step) * p[j] + step * mean;
                ss = fmaf(v[j], v[j], ss);
            }
#pragma unroll
            for (int m2 = 1; m2 < 64; m2 <<= 1) ss += __shfl_xor(ss, m2, 64);
            float inv = 1.f / fmaxf(sqrtf(ss), 1e-8f);
#pragma unroll
            for (int j = 0; j < 12; ++j) p[j] = v[j] * inv;
        }
    }

#pragma unroll
    for (int j = 0; j < 12; ++j) pout[k * CC + j * 64 + lane] = p[j];
}

// ---------------- K5: tail = blend (blocks 0..19) + loss (block 20) ----------------
__global__ __launch_bounds__(256) void k_tail(const float* __restrict__ feats,
                                              const float* __restrict__ fg,
                                              const float* __restrict__ bg,
                                              const float* __restrict__ pfg,
                                              const float* __restrict__ pbg,
                                              float* __restrict__ out) {
    const int r = blockIdx.x, tid = threadIdx.x;

    if (r < 20) {
        __shared__ float red[256];
        const float* a = (r < 10) ? (fg + r * CC) : (bg + (r - 10) * CC);
        const float* b = (r < 10) ? (pfg + r * CC) : (pbg + (r - 10) * CC);
        float v[3]; float ss = 0.f;
#pragma unroll
        for (int cc = 0; cc < 3; ++cc) {
            int c = tid + cc * 256;
            v[cc] = (1.0f - 0.3f) * a[c] + 0.3f * b[c];
            ss += v[cc] * v[cc];
        }
        red[tid] = ss; __syncthreads();
        for (int off = 128; off > 0; off >>= 1) { if (tid < off) red[tid] += red[tid + off]; __syncthreads(); }
        float inv = 1.f / fmaxf(sqrtf(red[0]), 1e-8f);
        float* o = out + 1 + r * CC;
#pragma unroll
        for (int cc = 0; cc < 3; ++cc) o[tid + cc * 256] = v[cc] * inv;
        return;
    }

    // ---- loss block ----
    __shared__ float dots3[NS * 30];   // [s][g*10+k]: g=0 pos@pfg, g=1 neg@pfg, g=2 pos@pbg
    __shared__ float mp[NS], mn[NS], infon[NS];
    int wave = tid >> 6, lane = tid & 63;

    for (int pid = wave; pid < 360; pid += 4) {
        int g = pid / 120, rr = pid % 120, s = rr / KP, k = rr % KP;
        const float4* a4 = (const float4*)(feats + ((g == 1 ? NS + s : s) * CC) + lane * 12);
        const float4* b4 = (const float4*)((g == 2 ? pbg : pfg) + k * CC + lane * 12);
        float acc = 0.f;
#pragma unroll
        for (int j = 0; j < 3; ++j) {
            float4 a = a4[j], b = b4[j];
            acc += a.x * b.x + a.y * b.y + a.z * b.z + a.w * b.w;
        }
#pragma unroll
        for (int m2 = 1; m2 < 64; m2 <<= 1) acc += __shfl_xor(acc, m2, 64);
        if (lane == 0) dots3[s * 30 + g * 10 + k] = acc;
    }
    __syncthreads();

    if (tid < NS) {
        const float* d = &dots3[tid * 30];
        float maxp = d[0], maxn = d[10];
#pragma unroll
        for (int k = 1; k < KP; ++k) { maxp = fmaxf(maxp, d[k]); maxn = fmaxf(maxn, d[10 + k]); }
        mp[tid] = maxp; mn[tid] = maxn;

        float x[KP], y[KP];
#pragma unroll
        for (int k = 0; k < KP; ++k) { x[k] = d[k] / 0.07f; y[k] = d[20 + k] / 0.07f; }
        float m10 = x[0];
#pragma unroll
        for (int k = 1; k < KP; ++k) m10 = fmaxf(m10, x[k]);
        float se = 0.f;
#pragma unroll
        for (int k = 0; k < KP; ++k) se += expf(x[k] - m10);
        float numer = logf(se) + m10;
        float m20 = m10;
#pragma unroll
        for (int k = 0; k < KP; ++k) m20 = fmaxf(m20, y[k]);
        float se2 = 0.f;
#pragma unroll
        for (int k = 0; k < KP; ++k) se2 += expf(x[k] - m20);
#pragma unroll
        for (int k = 0; k < KP; ++k) se2 += expf(y[k] - m20);
        float denom = logf(se2) + m20;
        infon[tid] = numer - denom;
    }
    __syncthreads();
    if (tid == 0) {
        float sp = 0.f, sn = 0.f, si = 0.f;
        for (int s = 0; s < NS; ++s) { sp += mp[s]; sn += mn[s]; si += infon[s]; }
        sp /= 12.f; sn /= 12.f; si /= 12.f;
        float loss = fmaxf(0.2f + sn - sp, 0.f) + 0.25f * (-si);
        out[0] = loss;
    }
}

extern "C" void kernel_launch(void* const* d_in, const int* in_sizes, int n_in,
                              void* d_out, int out_size, void* d_ws, size_t ws_size,
                              hipStream_t stream) {
    const float* fg = (const float*)d_in[0];   // [10,768]
    const float* bg = (const float*)d_in[1];   // [10,768]
    const float* F  = (const float*)d_in[2];   // [8,768,64,64]
    const float* M  = (const float*)d_in[3];   // [8,1,64,64]
    float* out = (float*)d_out;                // [1 + 7680 + 7680]

    float* w    = (float*)d_ws;
    int*   sel  = (int*)(w + WS_SEL);
    float* fea  = w + WS_FEATS;
    float* pfg  = w + WS_PFG;
    float* pbg  = w + WS_PBG;
    ull*   cand = (ull*)(w + WS_CAND);   // overlaps pfg; consumed before refine writes

    k_scores<<<256, 512, 0, stream>>>(fg, bg, F, M, w + WS_SCORE_FG, w + WS_SCORE_BG);
    k_topk1 <<<64, 256, 0, stream>>>(w, cand);
    k_topk2 <<<2, 384, 0, stream>>>(cand, sel);
    k_gather<<<24, 256, 0, stream>>>(F, sel, fea);
    k_refine<<<2, 640, 0, stream>>>(fea, fg, bg, pfg, pbg);
    k_tail  <<<21, 256, 0, stream>>>(fea, fg, bg, pfg, pbg, out);
}

// Round 10
// 154.759 us; speedup vs baseline: 1.2255x; 1.1205x over previous
//
#include <hip/hip_runtime.h>
#include <math.h>

// Problem constants
#define KP   10      // prototypes per side
#define CC   768     // channels
#define NB   8       // batch
#define HW   4096    // 64*64
#define STOT 32768   // NB*HW
#define NS   12      // N_SAMPLES

// Workspace layout (float offsets)
#define WS_SCORE_FG 0
#define WS_SCORE_BG 32768
#define WS_SEL      65536   // 24 ints (unused now, kept for layout stability)
#define WS_FEATS    65600   // 24*768 floats (pos 12 rows, then neg 12 rows)
#define WS_PFG      84032   // 10*768
#define WS_PBG      91712   // 10*768
// top-k candidates (2 sides x 384 u64) overlap WS_PFG: written by k_topk1,
// read by k_topk2g, and only later clobbered by k_refine's pfg output. Safe.
#define WS_CAND     84032

typedef unsigned long long ull;
typedef float f2v __attribute__((ext_vector_type(2)));   // clang vector: OK for nontemporal builtin

// ---------------- K1: per-pixel norm + max-sim scores ----------------
// 1024-thread blocks: 16 waves x 48 channels each; 2 pixels per lane
// (dwordx2 F loads). Grid 256 -> 16 waves/CU = 4/SIMD. All 20 prototypes
// staged in LDS (61 KB): proto reads are uniform-address ds_read_b128
// broadcasts on the LDS pipe -> VMEM pipe carries only the F stream.
// F non-temporal + 1-round prefetch. Scores bit-identical to R9.
__global__ __launch_bounds__(1024) void k_scores(const float* __restrict__ fg,
                                                 const float* __restrict__ bg,
                                                 const float* __restrict__ F,
                                                 const float* __restrict__ M,
                                                 float* __restrict__ sfg,
                                                 float* __restrict__ sbg) {
    __shared__ float pl[20 * CC];           // 61440 B: fg rows 0..9, bg rows 10..19
    __shared__ float part[8][64][2][21];    // 86016 B

    const int tid  = threadIdx.x;
    const int w    = __builtin_amdgcn_readfirstlane(tid >> 6);  // wave id 0..15
    const int lane = tid & 63;
    const int b    = blockIdx.x;            // 0..255
    const int n    = b >> 5;                // 32 blocks per image
    const int hwb  = (b & 31) * 128 + lane * 2;
    const float* fp = F + ((size_t)n * CC) * HW + hwb;
    const int cbase = w * 48;

    // prefetch first F round (independent of LDS)
    f2v fn[8];
#pragma unroll
    for (int j = 0; j < 8; ++j)
        fn[j] = __builtin_nontemporal_load((const f2v*)(fp + (size_t)(cbase + j) * HW));

    // stage protos to LDS
    for (int i = tid; i < KP * CC; i += 1024) {
        pl[i]            = fg[i];
        pl[KP * CC + i]  = bg[i];
    }
    __syncthreads();

    float afg[2][KP], abg[2][KP], n2[2];
#pragma unroll
    for (int k = 0; k < KP; ++k) { afg[0][k] = 0.f; afg[1][k] = 0.f; abg[0][k] = 0.f; abg[1][k] = 0.f; }
    n2[0] = 0.f; n2[1] = 0.f;

    for (int c0 = 0; c0 < 48; c0 += 8) {
        f2v f[8];
#pragma unroll
        for (int j = 0; j < 8; ++j) f[j] = fn[j];
        if (c0 + 8 < 48) {
#pragma unroll
            for (int j = 0; j < 8; ++j)
                fn[j] = __builtin_nontemporal_load((const f2v*)(fp + (size_t)(cbase + c0 + 8 + j) * HW));
        }

#pragma unroll
        for (int k = 0; k < KP; ++k) {
            const float4* pq = (const float4*)&pl[k * CC + cbase + c0];
            float4 a = pq[0], c = pq[1];
            float acc0 = afg[0][k], acc1 = afg[1][k];
            acc0 = fmaf(f[0].x, a.x, acc0); acc1 = fmaf(f[0].y, a.x, acc1);
            acc0 = fmaf(f[1].x, a.y, acc0); acc1 = fmaf(f[1].y, a.y, acc1);
            acc0 = fmaf(f[2].x, a.z, acc0); acc1 = fmaf(f[2].y, a.z, acc1);
            acc0 = fmaf(f[3].x, a.w, acc0); acc1 = fmaf(f[3].y, a.w, acc1);
            acc0 = fmaf(f[4].x, c.x, acc0); acc1 = fmaf(f[4].y, c.x, acc1);
            acc0 = fmaf(f[5].x, c.y, acc0); acc1 = fmaf(f[5].y, c.y, acc1);
            acc0 = fmaf(f[6].x, c.z, acc0); acc1 = fmaf(f[6].y, c.z, acc1);
            acc0 = fmaf(f[7].x, c.w, acc0); acc1 = fmaf(f[7].y, c.w, acc1);
            afg[0][k] = acc0; afg[1][k] = acc1;
        }
#pragma unroll
        for (int k = 0; k < KP; ++k) {
            const float4* pq = (const float4*)&pl[(KP + k) * CC + cbase + c0];
            float4 a = pq[0], c = pq[1];
            float acc0 = abg[0][k], acc1 = abg[1][k];
            acc0 = fmaf(f[0].x, a.x, acc0); acc1 = fmaf(f[0].y, a.x, acc1);
            acc0 = fmaf(f[1].x, a.y, acc0); acc1 = fmaf(f[1].y, a.y, acc1);
            acc0 = fmaf(f[2].x, a.z, acc0); acc1 = fmaf(f[2].y, a.z, acc1);
            acc0 = fmaf(f[3].x, a.w, acc0); acc1 = fmaf(f[3].y, a.w, acc1);
            acc0 = fmaf(f[4].x, c.x, acc0); acc1 = fmaf(f[4].y, c.x, acc1);
            acc0 = fmaf(f[5].x, c.y, acc0); acc1 = fmaf(f[5].y, c.y, acc1);
            acc0 = fmaf(f[6].x, c.z, acc0); acc1 = fmaf(f[6].y, c.z, acc1);
            acc0 = fmaf(f[7].x, c.w, acc0); acc1 = fmaf(f[7].y, c.w, acc1);
            abg[0][k] = acc0; abg[1][k] = acc1;
        }
#pragma unroll
        for (int j = 0; j < 8; ++j) {
            n2[0] = fmaf(f[j].x, f[j].x, n2[0]);
            n2[1] = fmaf(f[j].y, f[j].y, n2[1]);
        }
    }

    // fold 16 waves -> 8 slots: waves 8..15 write, waves 0..7 add in place
    if (w >= 8) {
#pragma unroll
        for (int px = 0; px < 2; ++px) {
#pragma unroll
            for (int k = 0; k < KP; ++k) {
                part[w - 8][lane][px][k]      = afg[px][k];
                part[w - 8][lane][px][10 + k] = abg[px][k];
            }
            part[w - 8][lane][px][20] = n2[px];
        }
    }
    __syncthreads();
    if (w < 8) {
#pragma unroll
        for (int px = 0; px < 2; ++px) {
#pragma unroll
            for (int k = 0; k < KP; ++k) {
                part[w][lane][px][k]      += afg[px][k];
                part[w][lane][px][10 + k] += abg[px][k];
            }
            part[w][lane][px][20] += n2[px];
        }
    }
    __syncthreads();

    // final: threads 0..127 -> (lane2, j) ; px = b*128 + tid (coalesced)
    if (tid < 128) {
        const int lane2 = tid >> 1, j = tid & 1;
        float vals[21];
#pragma unroll
        for (int q = 0; q < 21; ++q) {
            float acc = 0.f;
#pragma unroll
            for (int ss = 0; ss < 8; ++ss) acc += part[ss][lane2][j][q];
            vals[q] = acc;
        }
        float mfg = vals[0], mbg = vals[10];
#pragma unroll
        for (int k = 1; k < KP; ++k) { mfg = fmaxf(mfg, vals[k]); mbg = fmaxf(mbg, vals[10 + k]); }
        float nc = fmaxf(sqrtf(vals[20]), 1e-8f);
        int sp = b * 128 + tid;
        float m = fminf(fmaxf(M[sp], 0.f), 1.f);
        sfg[sp] = (1.f - mfg / nc) * m;
        sbg[sp] = (1.f - mbg / nc) * (1.f - m);
    }
}

// Order-preserving float->uint map, packed with ~index for exact
// (value desc, index asc) ordering under unsigned max.
__device__ __forceinline__ ull pack_key(float v, int idx) {
    unsigned u = __float_as_uint(v);
    u ^= (unsigned)((int)u >> 31) | 0x80000000u;
    return ((ull)u << 32) | (ull)(0xFFFFFFFFu - (unsigned)idx);
}

// ---------------- K2a: top-12 stage 1 (64 blocks: 32 per side) ----------------
__global__ __launch_bounds__(256) void k_topk1(const float* __restrict__ ws,
                                               ull* __restrict__ cand) {
    const int side = blockIdx.x >> 5, blk = blockIdx.x & 31;
    const float4* sc4 = (const float4*)(ws + (side == 0 ? WS_SCORE_FG : WS_SCORE_BG));
    const int tid = threadIdx.x;
    const int wave = tid >> 6, lane = tid & 63;

    const int i4 = blk * 256 + tid;
    float4 v4 = sc4[i4];
    ull kk[4];
    kk[0] = pack_key(v4.x, 4 * i4 + 0);
    kk[1] = pack_key(v4.y, 4 * i4 + 1);
    kk[2] = pack_key(v4.z, 4 * i4 + 2);
    kk[3] = pack_key(v4.w, 4 * i4 + 3);

    __shared__ ull wbest[4];
    __shared__ ull win_sh;

    for (int r = 0; r < NS; ++r) {
        ull b = kk[0];
#pragma unroll
        for (int q = 1; q < 4; ++q) b = (kk[q] > b) ? kk[q] : b;
#pragma unroll
        for (int m2 = 1; m2 < 64; m2 <<= 1) {
            ull o = __shfl_xor(b, m2, 64);
            b = (o > b) ? o : b;
        }
        if (lane == 0) wbest[wave] = b;
        __syncthreads();
        if (tid == 0) {
            ull m = wbest[0];
#pragma unroll
            for (int ww = 1; ww < 4; ++ww) m = (wbest[ww] > m) ? wbest[ww] : m;
            win_sh = m;
            cand[side * 384 + blk * NS + r] = m;
        }
        __syncthreads();
        ull win = win_sh;
#pragma unroll
        for (int q = 0; q < 4; ++q) { if (kk[q] == win) kk[q] = 0ull; }
    }
}

// ---------------- K2b: top-12 merge + gather + normalize (2 blocks) ----------
// Block = side. Merges its 384 candidates to 12 indices, then gathers the
// 12 selected feature rows from F, row-normalizes, writes to feats.
__global__ __launch_bounds__(1024) void k_topk2g(const ull* __restrict__ cand,
                                                 const float* __restrict__ F,
                                                 float* __restrict__ feats) {
    const int side = blockIdx.x;
    const int tid  = threadIdx.x;
    const int wave = __builtin_amdgcn_readfirstlane(tid >> 6);  // 0..15
    const int lane = tid & 63;

    __shared__ ull   wbest[16];
    __shared__ ull   win_sh;
    __shared__ int   seli[NS];
    __shared__ float gl[NS * CC];   // 36 KB

    ull key = (tid < 384) ? cand[side * 384 + tid] : 0ull;

    for (int r = 0; r < NS; ++r) {
        ull b = key;
#pragma unroll
        for (int m2 = 1; m2 < 64; m2 <<= 1) {
            ull o = __shfl_xor(b, m2, 64);
            b = (o > b) ? o : b;
        }
        if (lane == 0) wbest[wave] = b;
        __syncthreads();
        if (tid == 0) {
            ull m = wbest[0];
#pragma unroll
            for (int ww = 1; ww < 16; ++ww) m = (wbest[ww] > m) ? wbest[ww] : m;
            win_sh = m;
            seli[r] = (int)(0xFFFFFFFFu - (unsigned)(m & 0xFFFFFFFFull));
        }
        __syncthreads();
        if (key == win_sh) key = 0ull;
    }

    // gather 12 rows x 768 channels into LDS
    for (int i = tid; i < NS * CC; i += 1024) {
        int srow = i / CC, c = i - srow * CC;
        int sp = seli[srow];
        int nn = sp >> 12, hh = sp & 4095;
        gl[i] = F[((size_t)nn * CC + c) * HW + hh];
    }
    __syncthreads();

    // row-normalize: wave r (<12) handles row r; write to global feats
    if (wave < NS) {
        float ssq = 0.f;
#pragma unroll
        for (int j = 0; j < 12; ++j) { float v = gl[wave * CC + j * 64 + lane]; ssq = fmaf(v, v, ssq); }
#pragma unroll
        for (int m2 = 1; m2 < 64; m2 <<= 1) ssq += __shfl_xor(ssq, m2, 64);
        float inv = 1.f / fmaxf(sqrtf(ssq), 1e-8f);
#pragma unroll
        for (int j = 0; j < 12; ++j)
            feats[side * (NS * CC) + wave * CC + j * 64 + lane] = gl[wave * CC + j * 64 + lane] * inv;
    }
}

// ---------------- K4: refinement, one wave per prototype ----------------
__global__ __launch_bounds__(640) void k_refine(const float* __restrict__ feats_all,
                                                const float* __restrict__ fg,
                                                const float* __restrict__ bg,
                                                float* __restrict__ pfg,
                                                float* __restrict__ pbg) {
    __shared__ float fe[NS * CC];
    __shared__ float dots[NS][KP];
    __shared__ int   assign[NS];

    const int tid  = threadIdx.x;
    const int k    = __builtin_amdgcn_readfirstlane(tid >> 6);   // wave id = proto id
    const int lane = tid & 63;
    const float* feats = feats_all + blockIdx.x * (NS * CC);
    const float* p0    = (blockIdx.x == 0) ? fg : bg;
    float* pout        = (blockIdx.x == 0) ? pfg : pbg;

    for (int i = tid; i < NS * CC; i += 640) fe[i] = feats[i];
    float p[12];
#pragma unroll
    for (int j = 0; j < 12; ++j) p[j] = p0[k * CC + j * 64 + lane];
    __syncthreads();

    for (int it = 0; it < 10; ++it) {
        float step = 0.1f / (1.0f + 0.5f * (float)it);

        float d[NS];
#pragma unroll
        for (int s = 0; s < NS; ++s) d[s] = 0.f;
#pragma unroll
        for (int j = 0; j < 12; ++j) {
            float pvj = p[j];
#pragma unroll
            for (int s = 0; s < NS; ++s) d[s] = fmaf(fe[s * CC + j * 64 + lane], pvj, d[s]);
        }
#pragma unroll
        for (int s = 0; s < NS; ++s) {
#pragma unroll
            for (int m2 = 1; m2 < 64; m2 <<= 1) d[s] += __shfl_xor(d[s], m2, 64);
        }
        if (lane == 0) {
#pragma unroll
            for (int s = 0; s < NS; ++s) dots[s][k] = d[s];
        }
        __syncthreads();

        if (tid < NS) {
            float bv = dots[tid][0]; int bk = 0;
#pragma unroll
            for (int kk = 1; kk < KP; ++kk) { float v = dots[tid][kk]; if (v > bv) { bv = v; bk = kk; } }
            assign[tid] = bk;
        }
        __syncthreads();

        int a[NS]; int cnt = 0;
#pragma unroll
        for (int s = 0; s < NS; ++s) { a[s] = assign[s]; cnt += (a[s] == k) ? 1 : 0; }

        if (cnt > 0) {
            float mac[12];
#pragma unroll
            for (int j = 0; j < 12; ++j) mac[j] = 0.f;
#pragma unroll
            for (int s = 0; s < NS; ++s) {
                if (a[s] == k) {   // wave-uniform branch
#pragma unroll
                    for (int j = 0; j < 12; ++j) mac[j] += fe[s * CC + j * 64 + lane];
                }
            }
            float fcnt = (float)cnt;
            float v[12]; float ss = 0.f;
#pragma unroll
            for (int j = 0; j < 12; ++j) {
                float mean = mac[j] / fcnt;
                v[j] = (1.0f - step) * p[j] + step * mean;
                ss = fmaf(v[j], v[j], ss);
            }
#pragma unroll
            for (int m2 = 1; m2 < 64; m2 <<= 1) ss += __shfl_xor(ss, m2, 64);
            float inv = 1.f / fmaxf(sqrtf(ss), 1e-8f);
#pragma unroll
            for (int j = 0; j < 12; ++j) p[j] = v[j] * inv;
        }
    }

#pragma unroll
    for (int j = 0; j < 12; ++j) pout[k * CC + j * 64 + lane] = p[j];
}

// ---------------- K5: tail = blend (blocks 0..19) + loss (block 20) ----------------
__global__ __launch_bounds__(256) void k_tail(const float* __restrict__ feats,
                                              const float* __restrict__ fg,
                                              const float* __restrict__ bg,
                                              const float* __restrict__ pfg,
                                              const float* __restrict__ pbg,
                                              float* __restrict__ out) {
    const int r = blockIdx.x, tid = threadIdx.x;

    if (r < 20) {
        __shared__ float red[256];
        const float* a = (r < 10) ? (fg + r * CC) : (bg + (r - 10) * CC);
        const float* b = (r < 10) ? (pfg + r * CC) : (pbg + (r - 10) * CC);
        float v[3]; float ss = 0.f;
#pragma unroll
        for (int cc = 0; cc < 3; ++cc) {
            int c = tid + cc * 256;
            v[cc] = (1.0f - 0.3f) * a[c] + 0.3f * b[c];
            ss += v[cc] * v[cc];
        }
        red[tid] = ss; __syncthreads();
        for (int off = 128; off > 0; off >>= 1) { if (tid < off) red[tid] += red[tid + off]; __syncthreads(); }
        float inv = 1.f / fmaxf(sqrtf(red[0]), 1e-8f);
        float* o = out + 1 + r * CC;
#pragma unroll
        for (int cc = 0; cc < 3; ++cc) o[tid + cc * 256] = v[cc] * inv;
        return;
    }

    // ---- loss block ----
    __shared__ float dots3[NS * 30];   // [s][g*10+k]: g=0 pos@pfg, g=1 neg@pfg, g=2 pos@pbg
    __shared__ float mp[NS], mn[NS], infon[NS];
    int wave = tid >> 6, lane = tid & 63;

    for (int pid = wave; pid < 360; pid += 4) {
        int g = pid / 120, rr = pid % 120, s = rr / KP, k = rr % KP;
        const float4* a4 = (const float4*)(feats + ((g == 1 ? NS + s : s) * CC) + lane * 12);
        const float4* b4 = (const float4*)((g == 2 ? pbg : pfg) + k * CC + lane * 12);
        float acc = 0.f;
#pragma unroll
        for (int j = 0; j < 3; ++j) {
            float4 a = a4[j], b = b4[j];
            acc += a.x * b.x + a.y * b.y + a.z * b.z + a.w * b.w;
        }
#pragma unroll
        for (int m2 = 1; m2 < 64; m2 <<= 1) acc += __shfl_xor(acc, m2, 64);
        if (lane == 0) dots3[s * 30 + g * 10 + k] = acc;
    }
    __syncthreads();

    if (tid < NS) {
        const float* d = &dots3[tid * 30];
        float maxp = d[0], maxn = d[10];
#pragma unroll
        for (int k = 1; k < KP; ++k) { maxp = fmaxf(maxp, d[k]); maxn = fmaxf(maxn, d[10 + k]); }
        mp[tid] = maxp; mn[tid] = maxn;

        float x[KP], y[KP];
#pragma unroll
        for (int k = 0; k < KP; ++k) { x[k] = d[k] / 0.07f; y[k] = d[20 + k] / 0.07f; }
        float m10 = x[0];
#pragma unroll
        for (int k = 1; k < KP; ++k) m10 = fmaxf(m10, x[k]);
        float se = 0.f;
#pragma unroll
        for (int k = 0; k < KP; ++k) se += expf(x[k] - m10);
        float numer = logf(se) + m10;
        float m20 = m10;
#pragma unroll
        for (int k = 0; k < KP; ++k) m20 = fmaxf(m20, y[k]);
        float se2 = 0.f;
#pragma unroll
        for (int k = 0; k < KP; ++k) se2 += expf(x[k] - m20);
#pragma unroll
        for (int k = 0; k < KP; ++k) se2 += expf(y[k] - m20);
        float denom = logf(se2) + m20;
        infon[tid] = numer - denom;
    }
    __syncthreads();
    if (tid == 0) {
        float sp = 0.f, sn = 0.f, si = 0.f;
        for (int s = 0; s < NS; ++s) { sp += mp[s]; sn += mn[s]; si += infon[s]; }
        sp /= 12.f; sn /= 12.f; si /= 12.f;
        float loss = fmaxf(0.2f + sn - sp, 0.f) + 0.25f * (-si);
        out[0] = loss;
    }
}

extern "C" void kernel_launch(void* const* d_in, const int* in_sizes, int n_in,
                              void* d_out, int out_size, void* d_ws, size_t ws_size,
                              hipStream_t stream) {
    const float* fg = (const float*)d_in[0];   // [10,768]
    const float* bg = (const float*)d_in[1];   // [10,768]
    const float* F  = (const float*)d_in[2];   // [8,768,64,64]
    const float* M  = (const float*)d_in[3];   // [8,1,64,64]
    float* out = (float*)d_out;                // [1 + 7680 + 7680]

    float* w    = (float*)d_ws;
    float* fea  = w + WS_FEATS;
    float* pfg  = w + WS_PFG;
    float* pbg  = w + WS_PBG;
    ull*   cand = (ull*)(w + WS_CAND);   // overlaps pfg; consumed before refine writes

    k_scores<<<256, 1024, 0, stream>>>(fg, bg, F, M, w + WS_SCORE_FG, w + WS_SCORE_BG);
    k_topk1 <<<64, 256, 0, stream>>>(w, cand);
    k_topk2g<<<2, 1024, 0, stream>>>(cand, F, fea);
    k_refine<<<2, 640, 0, stream>>>(fea, fg, bg, pfg, pbg);
    k_tail  <<<21, 256, 0, stream>>>(fea, fg, bg, pfg, pbg, out);
}